// Round 15
// baseline (419.202 us; speedup 1.0000x reference)
//
#include <hip/hip_runtime.h>
#include <math.h>

#define B_ 2
#define L_ 4096
#define DM 1024
#define DI 2048
#define HD 64
#define NH 32
#define DS 128
#define CH 256
#define NC 16
#define DPROJ 4384   // 2*DI + 2*DS + NH
#define CONVD 2304   // DI + 2*DS
#define NGEMM 4352   // z + xBC columns (dt handled separately)

typedef unsigned short u16;
typedef unsigned int u32;
typedef __attribute__((ext_vector_type(8))) short bf16x8;
typedef __attribute__((ext_vector_type(4))) float f32x4;

__device__ __forceinline__ float silu_(float x) { return x / (1.0f + __expf(-x)); }
__device__ __forceinline__ float us2f(u16 u) {
  union { u32 i; float f; } c; c.i = ((u32)u) << 16; return c.f;
}
__device__ __forceinline__ u16 f2us(float f) {
  union { float f; u32 i; } c; c.f = f;
  u32 i = c.i;
  return (u16)((i + 0x7FFFu + ((i >> 16) & 1u)) >> 16);  // round-nearest-even
}
__device__ __forceinline__ void unpack8(uint4 v, float* o) {
  o[0] = us2f(v.x & 0xffffu); o[1] = us2f(v.x >> 16);
  o[2] = us2f(v.y & 0xffffu); o[3] = us2f(v.y >> 16);
  o[4] = us2f(v.z & 0xffffu); o[5] = us2f(v.z >> 16);
  o[6] = us2f(v.w & 0xffffu); o[7] = us2f(v.w >> 16);
}
__device__ __forceinline__ void unpk16(uint4 v, u16* o) {
  o[0] = (u16)(v.x & 0xffffu); o[1] = (u16)(v.x >> 16);
  o[2] = (u16)(v.y & 0xffffu); o[3] = (u16)(v.y >> 16);
  o[4] = (u16)(v.z & 0xffffu); o[5] = (u16)(v.z >> 16);
  o[6] = (u16)(v.w & 0xffffu); o[7] = (u16)(v.w >> 16);
}
__device__ __forceinline__ bf16x8 scale8(bf16x8 a, float s) {
  bf16x8 r;
#pragma unroll
  for (int j = 0; j < 8; ++j) r[j] = (short)f2us(us2f((u16)a[j]) * s);
  return r;
}
__device__ __forceinline__ void gload16(const u16* g, u16* l) {
  __builtin_amdgcn_global_load_lds(
      (const __attribute__((address_space(1))) void*)g,
      (__attribute__((address_space(3))) void*)l, 16, 0, 0);
}

// ==== fused prep: dt(fp32)+x->bf16 | W_in transpose | W_out transpose*nw ====
__global__ __launch_bounds__(256) void prep_k(const float* __restrict__ x,
                                              const float* __restrict__ W_in,
                                              const float* __restrict__ W_out,
                                              const float* __restrict__ nw,
                                              const float* __restrict__ dtb,
                                              float* __restrict__ dtp,
                                              u16* __restrict__ xb16,
                                              u16* __restrict__ wint,
                                              u16* __restrict__ woutt) {
  __shared__ float shmem[8 * 1024];
  const int t = threadIdx.x;
  const int bid = blockIdx.x;
  if (bid < 1024) {
    const int row0 = bid * 8;
#pragma unroll
    for (int i = 0; i < 8; ++i) {
      int j4 = i * 256 + t;
      float4 v = *(const float4*)&x[(size_t)row0 * DM + j4 * 4];
      *(float4*)&shmem[j4 * 4] = v;
      u32 lo = (u32)f2us(v.x) | ((u32)f2us(v.y) << 16);
      u32 hi = (u32)f2us(v.z) | ((u32)f2us(v.w) << 16);
      *(uint2*)&xb16[(size_t)row0 * DM + j4 * 4] = make_uint2(lo, hi);
    }
    __syncthreads();
    const int r = t >> 5, h = t & 31;
    float a0 = 0.f, a1 = 0.f, a2 = 0.f, a3 = 0.f;
    const float* wcol = W_in + (DI + CONVD) + h;
    const float* xr = &shmem[r * 1024];
    for (int k = 0; k < 1024; k += 4) {
      float4 xv = *(const float4*)&xr[k];
      a0 += xv.x * wcol[(size_t)(k + 0) * DPROJ];
      a1 += xv.y * wcol[(size_t)(k + 1) * DPROJ];
      a2 += xv.z * wcol[(size_t)(k + 2) * DPROJ];
      a3 += xv.w * wcol[(size_t)(k + 3) * DPROJ];
    }
    float v = (a0 + a1) + (a2 + a3) + dtb[h];
    dtp[(size_t)(row0 + r) * NH + h] = (v > 20.0f) ? v : log1pf(__expf(v));
  } else {
    float (*tile)[65] = (float(*)[65])shmem;
    const float* W; u16* Wt; int ldW, ldT, n0, k0; bool fold;
    if (bid < 2112) {
      int j = bid - 1024;
      W = W_in; Wt = wint; ldW = DPROJ; ldT = DM; fold = false;
      n0 = (j % (NGEMM / 64)) * 64; k0 = (j / (NGEMM / 64)) * 64;
    } else {
      int j = bid - 2112;
      W = W_out; Wt = woutt; ldW = DM; ldT = DI; fold = true;
      n0 = (j % (DM / 64)) * 64; k0 = (j / (DM / 64)) * 64;
    }
#pragma unroll
    for (int i = 0; i < 16; ++i) {
      int j = i * 256 + t;
      int kk = j >> 6, nn = j & 63;
      float v = W[(size_t)(k0 + kk) * ldW + n0 + nn];
      if (fold) v *= nw[k0 + kk];
      tile[kk][nn] = v;
    }
    __syncthreads();
#pragma unroll
    for (int i = 0; i < 16; ++i) {
      int j = i * 256 + t;
      int nn = j >> 6, kk = j & 63;
      Wt[(size_t)(n0 + nn) * ldT + k0 + kk] = f2us(tile[kk][nn]);
    }
  }
}

// ==== 256x128 bf16 MFMA GEMM (in-proj) + fused causal conv+SiLU epilogue ====
// M-tiles are chunk-aligned (256 rows): conv taps are in-tile for local rows
// >= 3. prev3 carries the last 3 raw rows across the 4 epilogue passes.
// Raw values hit global xraw ONLY for tile-local rows {0,1,2,253,254,255};
// conv for rows ≡ 0,1,2 (mod 256) is finished by conv_fix_k.
__global__ __launch_bounds__(512, 4) void gemm_in_k(const u16* __restrict__ A,
                                                    const u16* __restrict__ Bt,
                                                    const float* __restrict__ cw,
                                                    const float* __restrict__ cb,
                                                    u16* __restrict__ zb,
                                                    u16* __restrict__ xraw,
                                                    u16* __restrict__ xbc,
                                                    int nwg) {
  __shared__ u16 pool[24576];   // Al[256][64] @0, Bl[128][64] @16384
  u16* Al = pool;
  u16* Bl = pool + 16384;
  const int t = threadIdx.x;
  const int w = t >> 6, lane = t & 63;
  const int fr = lane & 15, oct = lane >> 4;
  const int wm = w >> 1, wn = w & 1;
  const int q = nwg >> 3;
  const int wg = (blockIdx.x & 7) * q + (blockIdx.x >> 3);
  const int bm = wg / (NGEMM / 128), bn = wg % (NGEMM / 128);
  const int m0 = bm * 256, n0 = bn * 128;
  const int lr = lane >> 3, ls = lane & 7;
  const int gslot = (ls ^ lr) * 8;   // XOR involution: LDS[r][s] = G[r][s^(r&7)]

  f32x4 acc[4][4];
#pragma unroll
  for (int mm = 0; mm < 4; ++mm)
#pragma unroll
    for (int nn = 0; nn < 4; ++nn) acc[mm][nn] = (f32x4){0.f, 0.f, 0.f, 0.f};

  for (int k0 = 0; k0 < DM; k0 += 64) {
    if (k0) __syncthreads();
#pragma unroll
    for (int i = 0; i < 4; ++i) {
      const int rowA = w * 32 + i * 8;
      gload16(&A[(size_t)(m0 + rowA + lr) * DM + k0 + gslot], &Al[rowA * 64]);
    }
#pragma unroll
    for (int i = 0; i < 2; ++i) {
      const int rowB = w * 16 + i * 8;
      gload16(&Bt[(size_t)(n0 + rowB + lr) * DM + k0 + gslot], &Bl[rowB * 64]);
    }
    __syncthreads();
#pragma unroll
    for (int kk = 0; kk < 2; ++kk) {
      bf16x8 af[4], bfr[4];
#pragma unroll
      for (int mm = 0; mm < 4; ++mm)
        af[mm] = *(const bf16x8*)&Al[(wm * 64 + mm * 16 + fr) * 64 +
                                     (((kk * 4 + oct) ^ (fr & 7)) * 8)];
#pragma unroll
      for (int nn = 0; nn < 4; ++nn)
        bfr[nn] = *(const bf16x8*)&Bl[(wn * 64 + nn * 16 + fr) * 64 +
                                      (((kk * 4 + oct) ^ (fr & 7)) * 8)];
      __builtin_amdgcn_s_setprio(1);
#pragma unroll
      for (int mm = 0; mm < 4; ++mm)
#pragma unroll
        for (int nn = 0; nn < 4; ++nn)
          acc[mm][nn] = __builtin_amdgcn_mfma_f32_16x16x32_bf16(af[mm], bfr[nn],
                                                                acc[mm][nn], 0, 0, 0);
      __builtin_amdgcn_s_setprio(0);
    }
  }

  const bool isz = (n0 < DI);
  const int chb = n0 - DI;
  u16* Oh = pool;                 // [64][136]
  u16* prev3 = pool + 8704;       // [3][136]
#pragma unroll
  for (int P = 0; P < 4; ++P) {
    __syncthreads();
    if (wm == P) {
#pragma unroll
      for (int mm = 0; mm < 4; ++mm)
#pragma unroll
        for (int i = 0; i < 4; ++i) {
          int rloc = mm * 16 + oct * 4 + i;
#pragma unroll
          for (int nn = 0; nn < 4; ++nn)
            Oh[rloc * 136 + wn * 64 + nn * 16 + fr] = f2us(acc[mm][nn][i]);
        }
    }
    __syncthreads();
#pragma unroll
    for (int p = 0; p < 2; ++p) {
      int e = p * 512 + t;
      int row = e >> 4, cs = (e & 15) * 8;
      uint4 v = *(const uint4*)&Oh[row * 136 + cs];
      size_t grow = m0 + P * 64 + row;
      if (isz) {
        *(uint4*)&zb[grow * DI + n0 + cs] = v;
      } else {
        const int ccol = chb + cs;
        if ((P == 0 && row < 3) || (P == 3 && row >= 61))
          *(uint4*)&xraw[grow * CONVD + ccol] = v;
        if (P > 0 || row >= 3) {
          u16 rr[4][8];
#pragma unroll
          for (int k = 0; k < 4; ++k) {
            int rsrc = row - 3 + k;
            const u16* srow = (rsrc >= 0) ? &Oh[rsrc * 136] : &prev3[(3 + rsrc) * 136];
            *(uint4*)rr[k] = *(const uint4*)&srow[cs];
          }
          float a[8];
#pragma unroll
          for (int qq = 0; qq < 8; ++qq) {
            float4 wv = *(const float4*)&cw[(ccol + qq) * 4];
            a[qq] = cb[ccol + qq] + us2f(rr[0][qq]) * wv.x + us2f(rr[1][qq]) * wv.y +
                    us2f(rr[2][qq]) * wv.z + us2f(rr[3][qq]) * wv.w;
          }
          uint4 ov;
          ov.x = (u32)f2us(silu_(a[0])) | ((u32)f2us(silu_(a[1])) << 16);
          ov.y = (u32)f2us(silu_(a[2])) | ((u32)f2us(silu_(a[3])) << 16);
          ov.z = (u32)f2us(silu_(a[4])) | ((u32)f2us(silu_(a[5])) << 16);
          ov.w = (u32)f2us(silu_(a[6])) | ((u32)f2us(silu_(a[7])) << 16);
          *(uint4*)&xbc[grow * CONVD + ccol] = ov;
        }
      }
    }
    __syncthreads();   // all prev3 reads done before overwrite
    if (!isz && t < 51) {   // copy raw rows 61..63 -> prev3 (3 x 17 uint4 segs)
      int r = t / 17, c8 = (t % 17) * 8;
      *(uint4*)&prev3[r * 136 + c8] = *(const uint4*)&Oh[(61 + r) * 136 + c8];
    }
  }
}

// ---- conv fix-up for tile-boundary rows (l % 256 in {0,1,2}) ----------------
__global__ __launch_bounds__(256) void conv_fix_k(const u16* __restrict__ xraw,
                                                  const float* __restrict__ cw,
                                                  const float* __restrict__ cb,
                                                  u16* __restrict__ xbc) {
  int idx = blockIdx.x * 256 + threadIdx.x;   // 96 rows * 288 col-groups
  if (idx >= 96 * (CONVD / 8)) return;
  int colg = idx % (CONVD / 8);
  int rid = idx / (CONVD / 8);
  size_t l = (size_t)(rid / 3) * 256 + (rid % 3);
  int lb = (int)(l & (L_ - 1));
  int ch = colg * 8;
  const u16* src = xraw + l * CONVD + ch;
  float a[8], o[8];
#pragma unroll
  for (int qq = 0; qq < 8; ++qq) a[qq] = cb[ch + qq];
#pragma unroll
  for (int k = 0; k < 4; ++k) {
    int dl = 3 - k;          // tap offset (l - dl), weight cw[.*4 + k]
    if (lb >= dl) {
      uint4 v = *(const uint4*)(src - (size_t)dl * CONVD);
      unpack8(v, o);
#pragma unroll
      for (int qq = 0; qq < 8; ++qq) a[qq] += o[qq] * cw[(ch + qq) * 4 + k];
    }
  }
  uint4 ov;
  ov.x = (u32)f2us(silu_(a[0])) | ((u32)f2us(silu_(a[1])) << 16);
  ov.y = (u32)f2us(silu_(a[2])) | ((u32)f2us(silu_(a[3])) << 16);
  ov.z = (u32)f2us(silu_(a[4])) | ((u32)f2us(silu_(a[5])) << 16);
  ov.w = (u32)f2us(silu_(a[6])) | ((u32)f2us(silu_(a[7])) << 16);
  *(uint4*)&xbc[l * CONVD + ch] = ov;
}

// ---- bf16 MFMA GEMM 128x128 (out-proj): rowsum prologue + RMS epilogue ------
template <int KDIM, int NTN>
__global__ __launch_bounds__(256) void gemm_out_k(const u16* __restrict__ A,
                                                  const u16* __restrict__ Bt,
                                                  const float* __restrict__ psum,
                                                  float* __restrict__ outf,
                                                  int nwg) {
  __shared__ u16 pool[17408];
  __shared__ float rs_s[128];
  u16* Al = pool;
  u16* Bl = pool + 8192;
  const int t = threadIdx.x;
  const int wv = t >> 6, lane = t & 63;
  const int fr = lane & 15, oct = lane >> 4;
  const int wr = wv >> 1, wc = wv & 1;
  const int q = nwg >> 3;
  const int wg = (blockIdx.x & 7) * q + (blockIdx.x >> 3);
  const int bm = wg / NTN, bn = wg % NTN;
  const int m0 = bm * 128, n0 = bn * 128;

  if (t < 128) {
    const float4* p = (const float4*)&psum[(size_t)(m0 + t) * 32];
    float s = 0.0f;
#pragma unroll
    for (int i = 0; i < 8; ++i) {
      float4 v = p[i];
      s += (v.x + v.y) + (v.z + v.w);
    }
    rs_s[t] = rsqrtf(s * (1.0f / DI) + 1e-5f);
  }

  const int lr = lane >> 3, ls = lane & 7;
  const int gslot = (ls ^ lr) * 8;

  f32x4 acc[4][4];
#pragma unroll
  for (int mm = 0; mm < 4; ++mm)
#pragma unroll
    for (int nn = 0; nn < 4; ++nn) acc[mm][nn] = (f32x4){0.f, 0.f, 0.f, 0.f};

  for (int k0 = 0; k0 < KDIM; k0 += 64) {
    if (k0) __syncthreads();
#pragma unroll
    for (int i = 0; i < 4; ++i) {
      const int rowA = wv * 32 + i * 8;
      gload16(&A[(size_t)(m0 + rowA + lr) * KDIM + k0 + gslot], &Al[rowA * 64]);
      gload16(&Bt[(size_t)(n0 + rowA + lr) * KDIM + k0 + gslot], &Bl[rowA * 64]);
    }
    __syncthreads();
#pragma unroll
    for (int kk = 0; kk < 2; ++kk) {
      bf16x8 af[4], bfr[4];
#pragma unroll
      for (int mm = 0; mm < 4; ++mm)
        af[mm] = *(const bf16x8*)&Al[(wr * 64 + mm * 16 + fr) * 64 +
                                     (((kk * 4 + oct) ^ (fr & 7)) * 8)];
#pragma unroll
      for (int nn = 0; nn < 4; ++nn)
        bfr[nn] = *(const bf16x8*)&Bl[(wc * 64 + nn * 16 + fr) * 64 +
                                      (((kk * 4 + oct) ^ (fr & 7)) * 8)];
#pragma unroll
      for (int mm = 0; mm < 4; ++mm)
#pragma unroll
        for (int nn = 0; nn < 4; ++nn)
          acc[mm][nn] = __builtin_amdgcn_mfma_f32_16x16x32_bf16(af[mm], bfr[nn],
                                                                acc[mm][nn], 0, 0, 0);
    }
  }

#pragma unroll
  for (int P = 0; P < 2; ++P) {
    __syncthreads();
    float* Of = (float*)pool;  // [64][132]
    if (wr == P) {
#pragma unroll
      for (int mm = 0; mm < 4; ++mm)
#pragma unroll
        for (int i = 0; i < 4; ++i) {
          int rloc = mm * 16 + oct * 4 + i;
#pragma unroll
          for (int nn = 0; nn < 4; ++nn)
            Of[rloc * 132 + wc * 64 + nn * 16 + fr] = acc[mm][nn][i];
        }
    }
    __syncthreads();
#pragma unroll
    for (int p = 0; p < 8; ++p) {
      int e = p * 256 + t;
      int row = e >> 5, c4 = (e & 31) * 4;
      float s = rs_s[P * 64 + row];
      float4 v = *(const float4*)&Of[row * 132 + c4];
      v.x *= s; v.y *= s; v.z *= s; v.w *= s;
      *(float4*)&outf[(size_t)(m0 + P * 64 + row) * DM + n0 + c4] = v;
    }
  }
}

// ---- chunk end-states via MFMA -> bf16; computes+publishes Acs --------------
#define SLP 72
__global__ __launch_bounds__(256) void states_k(const u16* __restrict__ xbc,
                                                const float* __restrict__ dtp,
                                                const float* __restrict__ A_log,
                                                float* __restrict__ Acs,
                                                u16* __restrict__ st16) {
  __shared__ u16 BtT[128 * SLP];
  __shared__ u16 XtT[64 * SLP];
  __shared__ float acs_s[256];
  const int t = threadIdx.x;
  const int wv = t >> 6, lane = t & 63;
  const int fr = lane & 15, oct = lane >> 4;
  const int sw = (blockIdx.x & 7) * 128 + (blockIdx.x >> 3);  // XCD swizzle
  const int h = sw & 31, c = (sw >> 5) & 15, b = sw >> 9;
  const size_t acsb = (((size_t)b * NH + h) * NC + c) * CH;
  const size_t rowbase = (size_t)b * L_ + c * CH;

  if (t < 64) {
    const float Ah = -__expf(A_log[h]);
    const size_t base = (rowbase + t * 4) * NH + h;
    float v0 = dtp[base] * Ah;
    float v1 = dtp[base + NH] * Ah;
    float v2 = dtp[base + 2 * NH] * Ah;
    float v3 = dtp[base + 3 * NH] * Ah;
    float c1 = v0 + v1, c2 = c1 + v2, c3 = c2 + v3;
    float tot = c3;
#pragma unroll
    for (int off = 1; off < 64; off <<= 1) {
      float p = __shfl_up(tot, off, 64);
      if (t >= off) tot += p;
    }
    float excl = tot - c3;
    float4 ov = make_float4(excl + v0, excl + c1, excl + c2, excl + c3);
    *(float4*)&acs_s[t * 4] = ov;
    *(float4*)&Acs[acsb + t * 4] = ov;
  }
  __syncthreads();
  const float acs_last = acs_s[255];

  f32x4 acc[2][4];
#pragma unroll
  for (int mt = 0; mt < 2; ++mt)
#pragma unroll
    for (int pt = 0; pt < 4; ++pt) acc[mt][pt] = (f32x4){0.f, 0.f, 0.f, 0.f};

  for (int lt = 0; lt < 4; ++lt) {
    __syncthreads();
#pragma unroll
    for (int i = 0; i < 2; ++i) {
      int ci = i * 256 + t;
      int lp = ci >> 4, nk = ci & 15;
      int l0 = lp * 2;
      const u16* srcp = &xbc[(rowbase + lt * 64 + l0) * CONVD + DI + nk * 8];
      uint4 v0 = *(const uint4*)srcp;
      uint4 v1 = *(const uint4*)(srcp + CONVD);
      u16 a0[8], a1[8];
      unpk16(v0, a0); unpk16(v1, a1);
#pragma unroll
      for (int qq = 0; qq < 8; ++qq) {
        int r = nk * 8 + qq;
        u32 val = (u32)a0[qq] | ((u32)a1[qq] << 16);
        *(u32*)&BtT[r * SLP + ((((l0 >> 3) ^ (r >> 3)) & 7) << 3) + (l0 & 7)] = val;
      }
    }
    {
      int lp = t >> 3, pk = t & 7;
      int l0 = lp * 2;
      size_t row0 = rowbase + lt * 64 + l0;
      uint4 v0 = *(const uint4*)&xbc[row0 * CONVD + h * HD + pk * 8];
      uint4 v1 = *(const uint4*)&xbc[(row0 + 1) * CONVD + h * HD + pk * 8];
      float d0 = dtp[row0 * NH + h] * __expf(acs_last - acs_s[lt * 64 + l0]);
      float d1 = dtp[(row0 + 1) * NH + h] * __expf(acs_last - acs_s[lt * 64 + l0 + 1]);
      float o0[8], o1[8];
      unpack8(v0, o0); unpack8(v1, o1);
#pragma unroll
      for (int qq = 0; qq < 8; ++qq) {
        int r = pk * 8 + qq;
        u32 val = (u32)f2us(o0[qq] * d0) | ((u32)f2us(o1[qq] * d1) << 16);
        *(u32*)&XtT[r * SLP + ((((l0 >> 3) ^ (r >> 3)) & 7) << 3) + (l0 & 7)] = val;
      }
    }
    __syncthreads();
    __builtin_amdgcn_s_setprio(1);
#pragma unroll
    for (int ks = 0; ks < 2; ++ks) {
      bf16x8 afr[2], bfr[4];
#pragma unroll
      for (int mt = 0; mt < 2; ++mt) {
        int r = wv * 32 + mt * 16 + fr;
        afr[mt] = *(const bf16x8*)&BtT[r * SLP + ((((ks * 4 + oct) ^ (r >> 3)) & 7) << 3)];
      }
#pragma unroll
      for (int pt = 0; pt < 4; ++pt) {
        int r = pt * 16 + fr;
        bfr[pt] = *(const bf16x8*)&XtT[r * SLP + ((((ks * 4 + oct) ^ (r >> 3)) & 7) << 3)];
      }
#pragma unroll
      for (int mt = 0; mt < 2; ++mt)
#pragma unroll
        for (int pt = 0; pt < 4; ++pt)
          acc[mt][pt] = __builtin_amdgcn_mfma_f32_16x16x32_bf16(afr[mt], bfr[pt],
                                                                acc[mt][pt], 0, 0, 0);
    }
    __builtin_amdgcn_s_setprio(0);
  }
  size_t sbase = (((size_t)b * NC + c) * NH + h) * (size_t)(HD * DS);
#pragma unroll
  for (int mt = 0; mt < 2; ++mt)
#pragma unroll
    for (int pt = 0; pt < 4; ++pt) {
      int p = pt * 16 + fr;
      int n0 = wv * 32 + mt * 16 + oct * 4;
      u32 lo = (u32)f2us(acc[mt][pt][0]) | ((u32)f2us(acc[mt][pt][1]) << 16);
      u32 hi = (u32)f2us(acc[mt][pt][2]) | ((u32)f2us(acc[mt][pt][3]) << 16);
      *(uint2*)&st16[sbase + (size_t)p * DS + n0] = make_uint2(lo, hi);
    }
}

// ---- inter-chunk scan (bf16 states, fp32 carry) -----------------------------
__global__ __launch_bounds__(256) void scan_k(u16* __restrict__ st16,
                                              const float* __restrict__ Acs) {
  const int t = threadIdx.x;
  const int seg = blockIdx.x & 15;
  const int bh = blockIdx.x >> 4;
  const int h = bh & 31, b = bh >> 5;
  const int e2 = seg * 256 + t;
  const size_t acssb = ((size_t)b * NH + h) * NC * CH;
  float run0 = 0.0f, run1 = 0.0f;
#pragma unroll
  for (int c = 0; c < NC; ++c) {
    float dAl = __expf(Acs[acssb + (size_t)c * CH + (CH - 1)]);
    size_t e = (((size_t)b * NC + c) * NH + h) * (size_t)(HD * DS) + e2 * 2;
    u32 v = *(const u32*)&st16[e];
    float s0 = us2f((u16)(v & 0xffffu)), s1 = us2f((u16)(v >> 16));
    *(u32*)&st16[e] = (u32)f2us(run0) | ((u32)f2us(run1) << 16);
    run0 = fmaf(dAl, run0, s0);
    run1 = fmaf(dAl, run1, s1);
  }
}

// ---- merged SSD + gated-v + partial row-sums --------------------------------
#define SP 72
#define XOFF 8192
#define POFF 12800
__global__ __launch_bounds__(512, 4) void ssd_out_k(const u16* __restrict__ xbc,
                                                    const float* __restrict__ dtp,
                                                    const float* __restrict__ Acs,
                                                    const u16* __restrict__ st16,
                                                    const float* __restrict__ Dvec,
                                                    const u16* __restrict__ zb,
                                                    u16* __restrict__ v_out,
                                                    float* __restrict__ psum) {
  __shared__ u16 pool[31232];
  __shared__ float acs_s[256];
  const int t = threadIdx.x;
  const int w = t >> 6, lane = t & 63;
  const int fr = lane & 15, oct = lane >> 4;
  const int sw = (blockIdx.x & 7) * 128 + (blockIdx.x >> 3);  // XCD swizzle
  const int h = sw & 31, c = (sw >> 5) & 15, b = sw >> 9;
  const size_t acsb = (((size_t)b * NH + h) * NC + c) * CH;
  const size_t rowbase = (size_t)b * L_ + c * CH;
  if (t < 256) acs_s[t] = Acs[acsb + t];
  const size_t sb = (((size_t)b * NC + c) * NH + h) * (size_t)(HD * DS);
#pragma unroll
  for (int i = 0; i < 2; ++i) {
    int ci = i * 512 + t; int p = ci >> 4, nk = ci & 15;
    uint4 v = *(const uint4*)&st16[sb + (size_t)p * DS + nk * 8];
    *(uint4*)&pool[p * 136 + nk * 8] = v;
  }
  __syncthreads();
  bf16x8 ca[2][4];
#pragma unroll
  for (int mt = 0; mt < 2; ++mt)
#pragma unroll
    for (int kk = 0; kk < 4; ++kk)
      ca[mt][kk] = *(const bf16x8*)&xbc[(rowbase + w * 32 + mt * 16 + fr) * CONVD +
                                        DI + DS + kk * 32 + oct * 8];
  f32x4 acc_y[2][4];
#pragma unroll
  for (int mt = 0; mt < 2; ++mt)
#pragma unroll
    for (int pp4 = 0; pp4 < 4; ++pp4) acc_y[mt][pp4] = (f32x4){0.f, 0.f, 0.f, 0.f};

  {
    float eL0 = __expf(acs_s[w * 32 + fr]);
    float eL1 = __expf(acs_s[w * 32 + 16 + fr]);
    __builtin_amdgcn_s_setprio(1);
#pragma unroll
    for (int kk = 0; kk < 4; ++kk) {
      bf16x8 c0 = scale8(ca[0][kk], eL0);
      bf16x8 c1 = scale8(ca[1][kk], eL1);
#pragma unroll
      for (int pp4 = 0; pp4 < 4; ++pp4) {
        bf16x8 sf = *(const bf16x8*)&pool[(pp4 * 16 + fr) * 136 + kk * 32 + oct * 8];
        acc_y[0][pp4] = __builtin_amdgcn_mfma_f32_16x16x32_bf16(c0, sf, acc_y[0][pp4], 0, 0, 0);
        acc_y[1][pp4] = __builtin_amdgcn_mfma_f32_16x16x32_bf16(c1, sf, acc_y[1][pp4], 0, 0, 0);
      }
    }
    __builtin_amdgcn_s_setprio(0);
  }

  const int stmax = w >> 1, delta = (w & 1) << 5;
  for (int st = 0; st < 4; ++st) {
    __syncthreads();
#pragma unroll
    for (int i = 0; i < 2; ++i) {
      int ci = i * 512 + t; int ll = ci >> 4, ck = ci & 15;
      uint4 v = *(const uint4*)&xbc[(rowbase + st * 64 + ll) * CONVD + DI + ck * 8];
      *(uint4*)&pool[ll * 128 + ((ck * 8) ^ ((ll & 7) << 3))] = v;
    }
    if (t < 256) {
      int lp = t >> 3, pk = t & 7;
      int s0 = lp * 2;
      size_t row0 = rowbase + st * 64 + s0;
      uint4 v0 = *(const uint4*)&xbc[row0 * CONVD + h * HD + pk * 8];
      uint4 v1 = *(const uint4*)&xbc[(row0 + 1) * CONVD + h * HD + pk * 8];
      float d0 = dtp[row0 * NH + h];
      float d1 = dtp[(row0 + 1) * NH + h];
      float o0[8], o1[8];
      unpack8(v0, o0); unpack8(v1, o1);
#pragma unroll
      for (int qq = 0; qq < 8; ++qq) {
        int r = pk * 8 + qq;
        u32 val = (u32)f2us(o0[qq] * d0) | ((u32)f2us(o1[qq] * d1) << 16);
        *(u32*)&pool[XOFF + r * SP + ((((s0 >> 3) ^ (r >> 3)) & 7) << 3) + (s0 & 7)] = val;
      }
    }
    __syncthreads();
    if (st > stmax) continue;
    const bool diag = (st == stmax);
#pragma unroll
    for (int ss4 = 0; ss4 < 4; ++ss4) {
      bf16x8 bbf[4];
#pragma unroll
      for (int kk = 0; kk < 4; ++kk)
        bbf[kk] = *(const bf16x8*)&pool[(ss4 * 16 + fr) * 128 +
                                        ((kk * 32 + oct * 8) ^ ((fr & 7) << 3))];
      int s_in = ss4 * 16 + fr;
      float aS = acs_s[st * 64 + s_in];
#pragma unroll
      for (int mt = 0; mt < 2; ++mt) {
        f32x4 sacc = (f32x4){0.f, 0.f, 0.f, 0.f};
        __builtin_amdgcn_s_setprio(1);
#pragma unroll
        for (int kk = 0; kk < 4; ++kk)
          sacc = __builtin_amdgcn_mfma_f32_16x16x32_bf16(ca[mt][kk], bbf[kk], sacc, 0, 0, 0);
        __builtin_amdgcn_s_setprio(0);
#pragma unroll
        for (int i = 0; i < 4; ++i) {
          int r = mt * 16 + oct * 4 + i;
          float aL = acs_s[w * 32 + r];
          float wgt = (!diag || (s_in <= r + delta)) ? __expf(aL - aS) : 0.0f;
          pool[POFF + w * 2304 + r * SP + s_in] = f2us(sacc[i] * wgt);
        }
      }
    }
    bf16x8 pa[2][2];
#pragma unroll
    for (int mt = 0; mt < 2; ++mt)
#pragma unroll
      for (int k2 = 0; k2 < 2; ++k2)
        pa[mt][k2] = *(const bf16x8*)&pool[POFF + w * 2304 + (mt * 16 + fr) * SP +
                                           k2 * 32 + oct * 8];
    __builtin_amdgcn_s_setprio(1);
#pragma unroll
    for (int pp4 = 0; pp4 < 4; ++pp4) {
      int rx = pp4 * 16 + fr, xg = rx >> 3;
      bf16x8 xb0 = *(const bf16x8*)&pool[XOFF + rx * SP + (((oct) ^ xg) & 7) * 8];
      bf16x8 xb1 = *(const bf16x8*)&pool[XOFF + rx * SP + (((4 + oct) ^ xg) & 7) * 8];
#pragma unroll
      for (int mt = 0; mt < 2; ++mt) {
        acc_y[mt][pp4] = __builtin_amdgcn_mfma_f32_16x16x32_bf16(pa[mt][0], xb0, acc_y[mt][pp4], 0, 0, 0);
        acc_y[mt][pp4] = __builtin_amdgcn_mfma_f32_16x16x32_bf16(pa[mt][1], xb1, acc_y[mt][pp4], 0, 0, 0);
      }
    }
    __builtin_amdgcn_s_setprio(0);
  }

  const float Dh = Dvec[h];
  float rs[2][4];
#pragma unroll
  for (int mt = 0; mt < 2; ++mt)
#pragma unroll
    for (int i = 0; i < 4; ++i) {
      size_t row = rowbase + w * 32 + mt * 16 + oct * 4 + i;
      float rsum = 0.0f;
#pragma unroll
      for (int pp4 = 0; pp4 < 4; ++pp4) {
        int col = h * HD + pp4 * 16 + fr;
        float xs = us2f(xbc[row * CONVD + col]);
        float zz = us2f(zb[row * DI + col]);
        float vv = (acc_y[mt][pp4][i] + Dh * xs) * silu_(zz);
        v_out[row * DI + col] = f2us(vv);
        rsum += vv * vv;
      }
      rs[mt][i] = rsum;
    }
#pragma unroll
  for (int mt = 0; mt < 2; ++mt)
#pragma unroll
    for (int i = 0; i < 4; ++i) {
      float s = rs[mt][i];
#pragma unroll
      for (int off = 8; off >= 1; off >>= 1) s += __shfl_xor(s, off, 64);
      if (fr == 0) {
        size_t row = rowbase + w * 32 + mt * 16 + oct * 4 + i;
        psum[row * 32 + h] = s;
      }
    }
}

extern "C" void kernel_launch(void* const* d_in, const int* in_sizes, int n_in,
                              void* d_out, int out_size, void* d_ws, size_t ws_size,
                              hipStream_t stream) {
  const float* x      = (const float*)d_in[0];
  const float* W_in   = (const float*)d_in[1];
  const float* conv_w = (const float*)d_in[2];
  const float* conv_b = (const float*)d_in[3];
  const float* dt_b   = (const float*)d_in[4];
  const float* A_log  = (const float*)d_in[5];
  const float* Dvec   = (const float*)d_in[6];
  const float* norm_w = (const float*)d_in[7];
  const float* W_out  = (const float*)d_in[8];
  float* out = (float*)d_out;

  u16* zb       = (u16*)d_ws;                              // 33.55 MB
  u16* xbc      = zb + (size_t)B_ * L_ * DI;               // 37.75 MB
  float* dtp    = (float*)(xbc + (size_t)B_ * L_ * CONVD); // 1.05 MB
  float* Acs    = dtp + (size_t)B_ * L_ * NH;              // 1.05 MB
  u16* stregion = (u16*)(Acs + (size_t)B_ * NH * L_);      // 33.55 MB region
  u16* uni      = stregion + (size_t)B_ * NC * NH * HD * DS * 2;  // 37.75 MB
  u16* xraw = uni;   // boundary raw rows only
  u16* v    = uni;   // v = gated SSD output, aliases xraw (xraw dead by then)

  // stregion: xb16@0 | wint@16.78M | woutt@25.69M | psum@29.88M ; states16@0
  u16* xb16     = stregion;
  u16* wint     = stregion + (size_t)B_ * L_ * DM;
  u16* woutt    = wint + (size_t)NGEMM * DM;
  float* psum   = (float*)(woutt + (size_t)DM * DI);
  u16* states16 = stregion;   // reuses xb16/wint space after gemm_in

  const int Mrows = B_ * L_;

  prep_k<<<1024 + (NGEMM / 64) * (DM / 64) + (DM / 64) * (DI / 64), 256, 0, stream>>>(
      x, W_in, W_out, norm_w, dt_b, dtp, xb16, wint, woutt);

  const int nwg_in = (Mrows / 256) * (NGEMM / 128);   // 1088
  gemm_in_k<<<nwg_in, 512, 0, stream>>>(xb16, wint, conv_w, conv_b, zb, xraw, xbc, nwg_in);

  conv_fix_k<<<(96 * (CONVD / 8) + 255) / 256, 256, 0, stream>>>(xraw, conv_w, conv_b, xbc);

  states_k<<<B_ * NC * NH, 256, 0, stream>>>(xbc, dtp, A_log, Acs, states16);
  scan_k<<<B_ * NH * 16, 256, 0, stream>>>(states16, Acs);
  ssd_out_k<<<B_ * NC * NH, 512, 0, stream>>>(xbc, dtp, Acs, states16, Dvec,
                                              zb, v, psum);

  const int nwg_out = (Mrows / 128) * (DM / 128);     // 512
  gemm_out_k<DI, DM / 128><<<nwg_out, 256, 0, stream>>>(v, woutt, psum, out, nwg_out);
}

// Round 16
// 336.680 us; speedup vs baseline: 1.2451x; 1.2451x over previous
//
#include <hip/hip_runtime.h>
#include <math.h>

#define B_ 2
#define L_ 4096
#define DM 1024
#define DI 2048
#define HD 64
#define NH 32
#define DS 128
#define CH 256
#define NC 16
#define DPROJ 4384   // 2*DI + 2*DS + NH
#define CONVD 2304   // DI + 2*DS
#define NGEMM 4352   // z + xBC columns (dt handled separately)

typedef unsigned short u16;
typedef unsigned int u32;
typedef __attribute__((ext_vector_type(8))) short bf16x8;
typedef __attribute__((ext_vector_type(4))) float f32x4;

__device__ __forceinline__ float silu_(float x) { return x / (1.0f + __expf(-x)); }
__device__ __forceinline__ float us2f(u16 u) {
  union { u32 i; float f; } c; c.i = ((u32)u) << 16; return c.f;
}
__device__ __forceinline__ u16 f2us(float f) {
  union { float f; u32 i; } c; c.f = f;
  u32 i = c.i;
  return (u16)((i + 0x7FFFu + ((i >> 16) & 1u)) >> 16);  // round-nearest-even
}
__device__ __forceinline__ void unpack8(uint4 v, float* o) {
  o[0] = us2f(v.x & 0xffffu); o[1] = us2f(v.x >> 16);
  o[2] = us2f(v.y & 0xffffu); o[3] = us2f(v.y >> 16);
  o[4] = us2f(v.z & 0xffffu); o[5] = us2f(v.z >> 16);
  o[6] = us2f(v.w & 0xffffu); o[7] = us2f(v.w >> 16);
}
__device__ __forceinline__ void unpk16(uint4 v, u16* o) {
  o[0] = (u16)(v.x & 0xffffu); o[1] = (u16)(v.x >> 16);
  o[2] = (u16)(v.y & 0xffffu); o[3] = (u16)(v.y >> 16);
  o[4] = (u16)(v.z & 0xffffu); o[5] = (u16)(v.z >> 16);
  o[6] = (u16)(v.w & 0xffffu); o[7] = (u16)(v.w >> 16);
}
__device__ __forceinline__ bf16x8 scale8(bf16x8 a, float s) {
  bf16x8 r;
#pragma unroll
  for (int j = 0; j < 8; ++j) r[j] = (short)f2us(us2f((u16)a[j]) * s);
  return r;
}
__device__ __forceinline__ void gload16(const u16* g, u16* l) {
  __builtin_amdgcn_global_load_lds(
      (const __attribute__((address_space(1))) void*)g,
      (__attribute__((address_space(3))) void*)l, 16, 0, 0);
}

// ==== fused prep: dt(fp32)+x->bf16 | W_in transpose | W_out transpose*nw ====
__global__ __launch_bounds__(256) void prep_k(const float* __restrict__ x,
                                              const float* __restrict__ W_in,
                                              const float* __restrict__ W_out,
                                              const float* __restrict__ nw,
                                              const float* __restrict__ dtb,
                                              float* __restrict__ dtp,
                                              u16* __restrict__ xb16,
                                              u16* __restrict__ wint,
                                              u16* __restrict__ woutt) {
  __shared__ float shmem[8 * 1024];
  const int t = threadIdx.x;
  const int bid = blockIdx.x;
  if (bid < 1024) {
    const int row0 = bid * 8;
#pragma unroll
    for (int i = 0; i < 8; ++i) {
      int j4 = i * 256 + t;
      float4 v = *(const float4*)&x[(size_t)row0 * DM + j4 * 4];
      *(float4*)&shmem[j4 * 4] = v;
      u32 lo = (u32)f2us(v.x) | ((u32)f2us(v.y) << 16);
      u32 hi = (u32)f2us(v.z) | ((u32)f2us(v.w) << 16);
      *(uint2*)&xb16[(size_t)row0 * DM + j4 * 4] = make_uint2(lo, hi);
    }
    __syncthreads();
    const int r = t >> 5, h = t & 31;
    float a0 = 0.f, a1 = 0.f, a2 = 0.f, a3 = 0.f;
    const float* wcol = W_in + (DI + CONVD) + h;
    const float* xr = &shmem[r * 1024];
    for (int k = 0; k < 1024; k += 4) {
      float4 xv = *(const float4*)&xr[k];
      a0 += xv.x * wcol[(size_t)(k + 0) * DPROJ];
      a1 += xv.y * wcol[(size_t)(k + 1) * DPROJ];
      a2 += xv.z * wcol[(size_t)(k + 2) * DPROJ];
      a3 += xv.w * wcol[(size_t)(k + 3) * DPROJ];
    }
    float v = (a0 + a1) + (a2 + a3) + dtb[h];
    dtp[(size_t)(row0 + r) * NH + h] = (v > 20.0f) ? v : log1pf(__expf(v));
  } else {
    float (*tile)[65] = (float(*)[65])shmem;
    const float* W; u16* Wt; int ldW, ldT, n0, k0; bool fold;
    if (bid < 2112) {
      int j = bid - 1024;
      W = W_in; Wt = wint; ldW = DPROJ; ldT = DM; fold = false;
      n0 = (j % (NGEMM / 64)) * 64; k0 = (j / (NGEMM / 64)) * 64;
    } else {
      int j = bid - 2112;
      W = W_out; Wt = woutt; ldW = DM; ldT = DI; fold = true;
      n0 = (j % (DM / 64)) * 64; k0 = (j / (DM / 64)) * 64;
    }
#pragma unroll
    for (int i = 0; i < 16; ++i) {
      int j = i * 256 + t;
      int kk = j >> 6, nn = j & 63;
      float v = W[(size_t)(k0 + kk) * ldW + n0 + nn];
      if (fold) v *= nw[k0 + kk];
      tile[kk][nn] = v;
    }
    __syncthreads();
#pragma unroll
    for (int i = 0; i < 16; ++i) {
      int j = i * 256 + t;
      int nn = j >> 6, kk = j & 63;
      Wt[(size_t)(n0 + nn) * ldT + k0 + kk] = f2us(tile[kk][nn]);
    }
  }
}

// ==== 256x128 bf16 MFMA GEMM (in-proj) ======================================
__global__ __launch_bounds__(512, 4) void gemm_in_k(const u16* __restrict__ A,
                                                    const u16* __restrict__ Bt,
                                                    u16* __restrict__ zb,
                                                    u16* __restrict__ xraw,
                                                    int nwg) {
  __shared__ u16 pool[24576];   // Al[256][64] @0, Bl[128][64] @16384
  u16* Al = pool;
  u16* Bl = pool + 16384;
  const int t = threadIdx.x;
  const int w = t >> 6, lane = t & 63;
  const int fr = lane & 15, oct = lane >> 4;
  const int wm = w >> 1, wn = w & 1;
  const int q = nwg >> 3;
  const int wg = (blockIdx.x & 7) * q + (blockIdx.x >> 3);
  const int bm = wg / (NGEMM / 128), bn = wg % (NGEMM / 128);
  const int m0 = bm * 256, n0 = bn * 128;
  const int lr = lane >> 3, ls = lane & 7;
  const int gslot = (ls ^ lr) * 8;   // XOR involution: LDS[r][s] = G[r][s^(r&7)]

  f32x4 acc[4][4];
#pragma unroll
  for (int mm = 0; mm < 4; ++mm)
#pragma unroll
    for (int nn = 0; nn < 4; ++nn) acc[mm][nn] = (f32x4){0.f, 0.f, 0.f, 0.f};

  for (int k0 = 0; k0 < DM; k0 += 64) {
    if (k0) __syncthreads();
#pragma unroll
    for (int i = 0; i < 4; ++i) {
      const int rowA = w * 32 + i * 8;
      gload16(&A[(size_t)(m0 + rowA + lr) * DM + k0 + gslot], &Al[rowA * 64]);
    }
#pragma unroll
    for (int i = 0; i < 2; ++i) {
      const int rowB = w * 16 + i * 8;
      gload16(&Bt[(size_t)(n0 + rowB + lr) * DM + k0 + gslot], &Bl[rowB * 64]);
    }
    __syncthreads();
#pragma unroll
    for (int kk = 0; kk < 2; ++kk) {
      bf16x8 af[4], bfr[4];
#pragma unroll
      for (int mm = 0; mm < 4; ++mm)
        af[mm] = *(const bf16x8*)&Al[(wm * 64 + mm * 16 + fr) * 64 +
                                     (((kk * 4 + oct) ^ (fr & 7)) * 8)];
#pragma unroll
      for (int nn = 0; nn < 4; ++nn)
        bfr[nn] = *(const bf16x8*)&Bl[(wn * 64 + nn * 16 + fr) * 64 +
                                      (((kk * 4 + oct) ^ (fr & 7)) * 8)];
      __builtin_amdgcn_s_setprio(1);
#pragma unroll
      for (int mm = 0; mm < 4; ++mm)
#pragma unroll
        for (int nn = 0; nn < 4; ++nn)
          acc[mm][nn] = __builtin_amdgcn_mfma_f32_16x16x32_bf16(af[mm], bfr[nn],
                                                                acc[mm][nn], 0, 0, 0);
      __builtin_amdgcn_s_setprio(0);
    }
  }

  const bool isz = (n0 < DI);
  u16* Oh = pool;
#pragma unroll
  for (int P = 0; P < 4; ++P) {
    __syncthreads();
    if (wm == P) {
#pragma unroll
      for (int mm = 0; mm < 4; ++mm)
#pragma unroll
        for (int i = 0; i < 4; ++i) {
          int rloc = mm * 16 + oct * 4 + i;
#pragma unroll
          for (int nn = 0; nn < 4; ++nn)
            Oh[rloc * 136 + wn * 64 + nn * 16 + fr] = f2us(acc[mm][nn][i]);
        }
    }
    __syncthreads();
#pragma unroll
    for (int p = 0; p < 2; ++p) {
      int e = p * 512 + t;
      int row = e >> 4, cs = (e & 15) * 8;
      uint4 v = *(const uint4*)&Oh[row * 136 + cs];
      size_t grow = m0 + P * 64 + row;
      int col = n0 + cs;
      if (isz) *(uint4*)&zb[grow * DI + col] = v;
      else     *(uint4*)&xraw[grow * CONVD + (col - DI)] = v;
    }
  }
}

// ---- bf16 MFMA GEMM 128x128 (out-proj): rowsum prologue + RMS epilogue ------
template <int KDIM, int NTN>
__global__ __launch_bounds__(256) void gemm_out_k(const u16* __restrict__ A,
                                                  const u16* __restrict__ Bt,
                                                  const float* __restrict__ psum,
                                                  float* __restrict__ outf,
                                                  int nwg) {
  __shared__ u16 pool[17408];
  __shared__ float rs_s[128];
  u16* Al = pool;
  u16* Bl = pool + 8192;
  const int t = threadIdx.x;
  const int wv = t >> 6, lane = t & 63;
  const int fr = lane & 15, oct = lane >> 4;
  const int wr = wv >> 1, wc = wv & 1;
  const int q = nwg >> 3;
  const int wg = (blockIdx.x & 7) * q + (blockIdx.x >> 3);
  const int bm = wg / NTN, bn = wg % NTN;
  const int m0 = bm * 128, n0 = bn * 128;

  if (t < 128) {
    const float4* p = (const float4*)&psum[(size_t)(m0 + t) * 32];
    float s = 0.0f;
#pragma unroll
    for (int i = 0; i < 8; ++i) {
      float4 v = p[i];
      s += (v.x + v.y) + (v.z + v.w);
    }
    rs_s[t] = rsqrtf(s * (1.0f / DI) + 1e-5f);
  }

  const int lr = lane >> 3, ls = lane & 7;
  const int gslot = (ls ^ lr) * 8;

  f32x4 acc[4][4];
#pragma unroll
  for (int mm = 0; mm < 4; ++mm)
#pragma unroll
    for (int nn = 0; nn < 4; ++nn) acc[mm][nn] = (f32x4){0.f, 0.f, 0.f, 0.f};

  for (int k0 = 0; k0 < KDIM; k0 += 64) {
    if (k0) __syncthreads();
#pragma unroll
    for (int i = 0; i < 4; ++i) {
      const int rowA = wv * 32 + i * 8;
      gload16(&A[(size_t)(m0 + rowA + lr) * KDIM + k0 + gslot], &Al[rowA * 64]);
      gload16(&Bt[(size_t)(n0 + rowA + lr) * KDIM + k0 + gslot], &Bl[rowA * 64]);
    }
    __syncthreads();
#pragma unroll
    for (int kk = 0; kk < 2; ++kk) {
      bf16x8 af[4], bfr[4];
#pragma unroll
      for (int mm = 0; mm < 4; ++mm)
        af[mm] = *(const bf16x8*)&Al[(wr * 64 + mm * 16 + fr) * 64 +
                                     (((kk * 4 + oct) ^ (fr & 7)) * 8)];
#pragma unroll
      for (int nn = 0; nn < 4; ++nn)
        bfr[nn] = *(const bf16x8*)&Bl[(wc * 64 + nn * 16 + fr) * 64 +
                                      (((kk * 4 + oct) ^ (fr & 7)) * 8)];
#pragma unroll
      for (int mm = 0; mm < 4; ++mm)
#pragma unroll
        for (int nn = 0; nn < 4; ++nn)
          acc[mm][nn] = __builtin_amdgcn_mfma_f32_16x16x32_bf16(af[mm], bfr[nn],
                                                                acc[mm][nn], 0, 0, 0);
    }
  }

#pragma unroll
  for (int P = 0; P < 2; ++P) {
    __syncthreads();
    float* Of = (float*)pool;  // [64][132]
    if (wr == P) {
#pragma unroll
      for (int mm = 0; mm < 4; ++mm)
#pragma unroll
        for (int i = 0; i < 4; ++i) {
          int rloc = mm * 16 + oct * 4 + i;
#pragma unroll
          for (int nn = 0; nn < 4; ++nn)
            Of[rloc * 132 + wc * 64 + nn * 16 + fr] = acc[mm][nn][i];
        }
    }
    __syncthreads();
#pragma unroll
    for (int p = 0; p < 8; ++p) {
      int e = p * 256 + t;
      int row = e >> 5, c4 = (e & 31) * 4;
      float s = rs_s[P * 64 + row];
      float4 v = *(const float4*)&Of[row * 132 + c4];
      v.x *= s; v.y *= s; v.z *= s; v.w *= s;
      *(float4*)&outf[(size_t)(m0 + P * 64 + row) * DM + n0 + c4] = v;
    }
  }
}

// ---- causal depthwise conv(4) + SiLU ----------------------------------------
__global__ __launch_bounds__(256) void conv_silu_k(const u16* __restrict__ xraw,
                                                   const float* __restrict__ cw,
                                                   const float* __restrict__ cb,
                                                   u16* __restrict__ xbc) {
  int idx = blockIdx.x * 256 + threadIdx.x;
  int ch8 = idx % (CONVD / 8);
  int bl = idx / (CONVD / 8);
  int l = bl & (L_ - 1);
  int ch = ch8 * 8;
  const u16* src = xraw + (size_t)bl * CONVD + ch;
  float a[8], o[8];
#pragma unroll
  for (int qq = 0; qq < 8; ++qq) a[qq] = cb[ch + qq];
  float w0[8], w1[8], w2[8], w3[8];
#pragma unroll
  for (int qq = 0; qq < 8; ++qq) {
    float4 w = *(const float4*)&cw[(ch + qq) * 4];
    w0[qq] = w.x; w1[qq] = w.y; w2[qq] = w.z; w3[qq] = w.w;
  }
  if (l >= 3) {
    uint4 v = *(const uint4*)&src[-3 * CONVD]; unpack8(v, o);
#pragma unroll
    for (int qq = 0; qq < 8; ++qq) a[qq] += o[qq] * w0[qq];
  }
  if (l >= 2) {
    uint4 v = *(const uint4*)&src[-2 * CONVD]; unpack8(v, o);
#pragma unroll
    for (int qq = 0; qq < 8; ++qq) a[qq] += o[qq] * w1[qq];
  }
  if (l >= 1) {
    uint4 v = *(const uint4*)&src[-CONVD]; unpack8(v, o);
#pragma unroll
    for (int qq = 0; qq < 8; ++qq) a[qq] += o[qq] * w2[qq];
  }
  {
    uint4 v = *(const uint4*)&src[0]; unpack8(v, o);
#pragma unroll
    for (int qq = 0; qq < 8; ++qq) a[qq] += o[qq] * w3[qq];
  }
  uint4 ov;
  ov.x = (u32)f2us(silu_(a[0])) | ((u32)f2us(silu_(a[1])) << 16);
  ov.y = (u32)f2us(silu_(a[2])) | ((u32)f2us(silu_(a[3])) << 16);
  ov.z = (u32)f2us(silu_(a[4])) | ((u32)f2us(silu_(a[5])) << 16);
  ov.w = (u32)f2us(silu_(a[6])) | ((u32)f2us(silu_(a[7])) << 16);
  *(uint4*)&xbc[(size_t)bl * CONVD + ch] = ov;
}

// ---- chunk end-states via MFMA -> bf16; computes+publishes Acs --------------
#define SLP 72
__global__ __launch_bounds__(256) void states_k(const u16* __restrict__ xbc,
                                                const float* __restrict__ dtp,
                                                const float* __restrict__ A_log,
                                                float* __restrict__ Acs,
                                                u16* __restrict__ st16) {
  __shared__ u16 BtT[128 * SLP];
  __shared__ u16 XtT[64 * SLP];
  __shared__ float acs_s[256];
  const int t = threadIdx.x;
  const int wv = t >> 6, lane = t & 63;
  const int fr = lane & 15, oct = lane >> 4;
  const int sw = (blockIdx.x & 7) * 128 + (blockIdx.x >> 3);  // XCD swizzle
  const int h = sw & 31, c = (sw >> 5) & 15, b = sw >> 9;
  const size_t acsb = (((size_t)b * NH + h) * NC + c) * CH;
  const size_t rowbase = (size_t)b * L_ + c * CH;

  if (t < 64) {
    const float Ah = -__expf(A_log[h]);
    const size_t base = (rowbase + t * 4) * NH + h;
    float v0 = dtp[base] * Ah;
    float v1 = dtp[base + NH] * Ah;
    float v2 = dtp[base + 2 * NH] * Ah;
    float v3 = dtp[base + 3 * NH] * Ah;
    float c1 = v0 + v1, c2 = c1 + v2, c3 = c2 + v3;
    float tot = c3;
#pragma unroll
    for (int off = 1; off < 64; off <<= 1) {
      float p = __shfl_up(tot, off, 64);
      if (t >= off) tot += p;
    }
    float excl = tot - c3;
    float4 ov = make_float4(excl + v0, excl + c1, excl + c2, excl + c3);
    *(float4*)&acs_s[t * 4] = ov;
    *(float4*)&Acs[acsb + t * 4] = ov;
  }
  __syncthreads();
  const float acs_last = acs_s[255];

  f32x4 acc[2][4];
#pragma unroll
  for (int mt = 0; mt < 2; ++mt)
#pragma unroll
    for (int pt = 0; pt < 4; ++pt) acc[mt][pt] = (f32x4){0.f, 0.f, 0.f, 0.f};

  for (int lt = 0; lt < 4; ++lt) {
    __syncthreads();
#pragma unroll
    for (int i = 0; i < 2; ++i) {
      int ci = i * 256 + t;
      int lp = ci >> 4, nk = ci & 15;
      int l0 = lp * 2;
      const u16* srcp = &xbc[(rowbase + lt * 64 + l0) * CONVD + DI + nk * 8];
      uint4 v0 = *(const uint4*)srcp;
      uint4 v1 = *(const uint4*)(srcp + CONVD);
      u16 a0[8], a1[8];
      unpk16(v0, a0); unpk16(v1, a1);
#pragma unroll
      for (int qq = 0; qq < 8; ++qq) {
        int r = nk * 8 + qq;
        u32 val = (u32)a0[qq] | ((u32)a1[qq] << 16);
        *(u32*)&BtT[r * SLP + ((((l0 >> 3) ^ (r >> 3)) & 7) << 3) + (l0 & 7)] = val;
      }
    }
    {
      int lp = t >> 3, pk = t & 7;
      int l0 = lp * 2;
      size_t row0 = rowbase + lt * 64 + l0;
      uint4 v0 = *(const uint4*)&xbc[row0 * CONVD + h * HD + pk * 8];
      uint4 v1 = *(const uint4*)&xbc[(row0 + 1) * CONVD + h * HD + pk * 8];
      float d0 = dtp[row0 * NH + h] * __expf(acs_last - acs_s[lt * 64 + l0]);
      float d1 = dtp[(row0 + 1) * NH + h] * __expf(acs_last - acs_s[lt * 64 + l0 + 1]);
      float o0[8], o1[8];
      unpack8(v0, o0); unpack8(v1, o1);
#pragma unroll
      for (int qq = 0; qq < 8; ++qq) {
        int r = pk * 8 + qq;
        u32 val = (u32)f2us(o0[qq] * d0) | ((u32)f2us(o1[qq] * d1) << 16);
        *(u32*)&XtT[r * SLP + ((((l0 >> 3) ^ (r >> 3)) & 7) << 3) + (l0 & 7)] = val;
      }
    }
    __syncthreads();
    __builtin_amdgcn_s_setprio(1);
#pragma unroll
    for (int ks = 0; ks < 2; ++ks) {
      bf16x8 afr[2], bfr[4];
#pragma unroll
      for (int mt = 0; mt < 2; ++mt) {
        int r = wv * 32 + mt * 16 + fr;
        afr[mt] = *(const bf16x8*)&BtT[r * SLP + ((((ks * 4 + oct) ^ (r >> 3)) & 7) << 3)];
      }
#pragma unroll
      for (int pt = 0; pt < 4; ++pt) {
        int r = pt * 16 + fr;
        bfr[pt] = *(const bf16x8*)&XtT[r * SLP + ((((ks * 4 + oct) ^ (r >> 3)) & 7) << 3)];
      }
#pragma unroll
      for (int mt = 0; mt < 2; ++mt)
#pragma unroll
        for (int pt = 0; pt < 4; ++pt)
          acc[mt][pt] = __builtin_amdgcn_mfma_f32_16x16x32_bf16(afr[mt], bfr[pt],
                                                                acc[mt][pt], 0, 0, 0);
    }
    __builtin_amdgcn_s_setprio(0);
  }
  size_t sbase = (((size_t)b * NC + c) * NH + h) * (size_t)(HD * DS);
#pragma unroll
  for (int mt = 0; mt < 2; ++mt)
#pragma unroll
    for (int pt = 0; pt < 4; ++pt) {
      int p = pt * 16 + fr;
      int n0 = wv * 32 + mt * 16 + oct * 4;
      u32 lo = (u32)f2us(acc[mt][pt][0]) | ((u32)f2us(acc[mt][pt][1]) << 16);
      u32 hi = (u32)f2us(acc[mt][pt][2]) | ((u32)f2us(acc[mt][pt][3]) << 16);
      *(uint2*)&st16[sbase + (size_t)p * DS + n0] = make_uint2(lo, hi);
    }
}

// ---- inter-chunk scan (bf16 states, fp32 carry) -----------------------------
__global__ __launch_bounds__(256) void scan_k(u16* __restrict__ st16,
                                              const float* __restrict__ Acs) {
  const int t = threadIdx.x;
  const int seg = blockIdx.x & 15;
  const int bh = blockIdx.x >> 4;
  const int h = bh & 31, b = bh >> 5;
  const int e2 = seg * 256 + t;
  const size_t acssb = ((size_t)b * NH + h) * NC * CH;
  float run0 = 0.0f, run1 = 0.0f;
#pragma unroll
  for (int c = 0; c < NC; ++c) {
    float dAl = __expf(Acs[acssb + (size_t)c * CH + (CH - 1)]);
    size_t e = (((size_t)b * NC + c) * NH + h) * (size_t)(HD * DS) + e2 * 2;
    u32 v = *(const u32*)&st16[e];
    float s0 = us2f((u16)(v & 0xffffu)), s1 = us2f((u16)(v >> 16));
    *(u32*)&st16[e] = (u32)f2us(run0) | ((u32)f2us(run1) << 16);
    run0 = fmaf(dAl, run0, s0);
    run1 = fmaf(dAl, run1, s1);
  }
}

// ---- merged SSD + gated-v + partial row-sums --------------------------------
#define SP 72
#define XOFF 8192
#define POFF 12800
__global__ __launch_bounds__(512, 4) void ssd_out_k(const u16* __restrict__ xbc,
                                                    const float* __restrict__ dtp,
                                                    const float* __restrict__ Acs,
                                                    const u16* __restrict__ st16,
                                                    const float* __restrict__ Dvec,
                                                    const u16* __restrict__ zb,
                                                    u16* __restrict__ v_out,
                                                    float* __restrict__ psum) {
  __shared__ u16 pool[31232];
  __shared__ float acs_s[256];
  const int t = threadIdx.x;
  const int w = t >> 6, lane = t & 63;
  const int fr = lane & 15, oct = lane >> 4;
  const int sw = (blockIdx.x & 7) * 128 + (blockIdx.x >> 3);  // XCD swizzle
  const int h = sw & 31, c = (sw >> 5) & 15, b = sw >> 9;
  const size_t acsb = (((size_t)b * NH + h) * NC + c) * CH;
  const size_t rowbase = (size_t)b * L_ + c * CH;
  if (t < 256) acs_s[t] = Acs[acsb + t];
  const size_t sb = (((size_t)b * NC + c) * NH + h) * (size_t)(HD * DS);
#pragma unroll
  for (int i = 0; i < 2; ++i) {
    int ci = i * 512 + t; int p = ci >> 4, nk = ci & 15;
    uint4 v = *(const uint4*)&st16[sb + (size_t)p * DS + nk * 8];
    *(uint4*)&pool[p * 136 + nk * 8] = v;
  }
  __syncthreads();
  bf16x8 ca[2][4];
#pragma unroll
  for (int mt = 0; mt < 2; ++mt)
#pragma unroll
    for (int kk = 0; kk < 4; ++kk)
      ca[mt][kk] = *(const bf16x8*)&xbc[(rowbase + w * 32 + mt * 16 + fr) * CONVD +
                                        DI + DS + kk * 32 + oct * 8];
  f32x4 acc_y[2][4];
#pragma unroll
  for (int mt = 0; mt < 2; ++mt)
#pragma unroll
    for (int pp4 = 0; pp4 < 4; ++pp4) acc_y[mt][pp4] = (f32x4){0.f, 0.f, 0.f, 0.f};

  {
    float eL0 = __expf(acs_s[w * 32 + fr]);
    float eL1 = __expf(acs_s[w * 32 + 16 + fr]);
    __builtin_amdgcn_s_setprio(1);
#pragma unroll
    for (int kk = 0; kk < 4; ++kk) {
      bf16x8 c0 = scale8(ca[0][kk], eL0);
      bf16x8 c1 = scale8(ca[1][kk], eL1);
#pragma unroll
      for (int pp4 = 0; pp4 < 4; ++pp4) {
        bf16x8 sf = *(const bf16x8*)&pool[(pp4 * 16 + fr) * 136 + kk * 32 + oct * 8];
        acc_y[0][pp4] = __builtin_amdgcn_mfma_f32_16x16x32_bf16(c0, sf, acc_y[0][pp4], 0, 0, 0);
        acc_y[1][pp4] = __builtin_amdgcn_mfma_f32_16x16x32_bf16(c1, sf, acc_y[1][pp4], 0, 0, 0);
      }
    }
    __builtin_amdgcn_s_setprio(0);
  }

  const int stmax = w >> 1, delta = (w & 1) << 5;
  for (int st = 0; st < 4; ++st) {
    __syncthreads();
#pragma unroll
    for (int i = 0; i < 2; ++i) {
      int ci = i * 512 + t; int ll = ci >> 4, ck = ci & 15;
      uint4 v = *(const uint4*)&xbc[(rowbase + st * 64 + ll) * CONVD + DI + ck * 8];
      *(uint4*)&pool[ll * 128 + ((ck * 8) ^ ((ll & 7) << 3))] = v;
    }
    if (t < 256) {
      int lp = t >> 3, pk = t & 7;
      int s0 = lp * 2;
      size_t row0 = rowbase + st * 64 + s0;
      uint4 v0 = *(const uint4*)&xbc[row0 * CONVD + h * HD + pk * 8];
      uint4 v1 = *(const uint4*)&xbc[(row0 + 1) * CONVD + h * HD + pk * 8];
      float d0 = dtp[row0 * NH + h];
      float d1 = dtp[(row0 + 1) * NH + h];
      float o0[8], o1[8];
      unpack8(v0, o0); unpack8(v1, o1);
#pragma unroll
      for (int qq = 0; qq < 8; ++qq) {
        int r = pk * 8 + qq;
        u32 val = (u32)f2us(o0[qq] * d0) | ((u32)f2us(o1[qq] * d1) << 16);
        *(u32*)&pool[XOFF + r * SP + ((((s0 >> 3) ^ (r >> 3)) & 7) << 3) + (s0 & 7)] = val;
      }
    }
    __syncthreads();
    if (st > stmax) continue;
    const bool diag = (st == stmax);
#pragma unroll
    for (int ss4 = 0; ss4 < 4; ++ss4) {
      bf16x8 bbf[4];
#pragma unroll
      for (int kk = 0; kk < 4; ++kk)
        bbf[kk] = *(const bf16x8*)&pool[(ss4 * 16 + fr) * 128 +
                                        ((kk * 32 + oct * 8) ^ ((fr & 7) << 3))];
      int s_in = ss4 * 16 + fr;
      float aS = acs_s[st * 64 + s_in];
#pragma unroll
      for (int mt = 0; mt < 2; ++mt) {
        f32x4 sacc = (f32x4){0.f, 0.f, 0.f, 0.f};
        __builtin_amdgcn_s_setprio(1);
#pragma unroll
        for (int kk = 0; kk < 4; ++kk)
          sacc = __builtin_amdgcn_mfma_f32_16x16x32_bf16(ca[mt][kk], bbf[kk], sacc, 0, 0, 0);
        __builtin_amdgcn_s_setprio(0);
#pragma unroll
        for (int i = 0; i < 4; ++i) {
          int r = mt * 16 + oct * 4 + i;
          float aL = acs_s[w * 32 + r];
          float wgt = (!diag || (s_in <= r + delta)) ? __expf(aL - aS) : 0.0f;
          pool[POFF + w * 2304 + r * SP + s_in] = f2us(sacc[i] * wgt);
        }
      }
    }
    bf16x8 pa[2][2];
#pragma unroll
    for (int mt = 0; mt < 2; ++mt)
#pragma unroll
      for (int k2 = 0; k2 < 2; ++k2)
        pa[mt][k2] = *(const bf16x8*)&pool[POFF + w * 2304 + (mt * 16 + fr) * SP +
                                           k2 * 32 + oct * 8];
    __builtin_amdgcn_s_setprio(1);
#pragma unroll
    for (int pp4 = 0; pp4 < 4; ++pp4) {
      int rx = pp4 * 16 + fr, xg = rx >> 3;
      bf16x8 xb0 = *(const bf16x8*)&pool[XOFF + rx * SP + (((oct) ^ xg) & 7) * 8];
      bf16x8 xb1 = *(const bf16x8*)&pool[XOFF + rx * SP + (((4 + oct) ^ xg) & 7) * 8];
#pragma unroll
      for (int mt = 0; mt < 2; ++mt) {
        acc_y[mt][pp4] = __builtin_amdgcn_mfma_f32_16x16x32_bf16(pa[mt][0], xb0, acc_y[mt][pp4], 0, 0, 0);
        acc_y[mt][pp4] = __builtin_amdgcn_mfma_f32_16x16x32_bf16(pa[mt][1], xb1, acc_y[mt][pp4], 0, 0, 0);
      }
    }
    __builtin_amdgcn_s_setprio(0);
  }

  const float Dh = Dvec[h];
  float rs[2][4];
#pragma unroll
  for (int mt = 0; mt < 2; ++mt)
#pragma unroll
    for (int i = 0; i < 4; ++i) {
      size_t row = rowbase + w * 32 + mt * 16 + oct * 4 + i;
      float rsum = 0.0f;
#pragma unroll
      for (int pp4 = 0; pp4 < 4; ++pp4) {
        int col = h * HD + pp4 * 16 + fr;
        float xs = us2f(xbc[row * CONVD + col]);
        float zz = us2f(zb[row * DI + col]);
        float vv = (acc_y[mt][pp4][i] + Dh * xs) * silu_(zz);
        v_out[row * DI + col] = f2us(vv);
        rsum += vv * vv;
      }
      rs[mt][i] = rsum;
    }
#pragma unroll
  for (int mt = 0; mt < 2; ++mt)
#pragma unroll
    for (int i = 0; i < 4; ++i) {
      float s = rs[mt][i];
#pragma unroll
      for (int off = 8; off >= 1; off >>= 1) s += __shfl_xor(s, off, 64);
      if (fr == 0) {
        size_t row = rowbase + w * 32 + mt * 16 + oct * 4 + i;
        psum[row * 32 + h] = s;
      }
    }
}

extern "C" void kernel_launch(void* const* d_in, const int* in_sizes, int n_in,
                              void* d_out, int out_size, void* d_ws, size_t ws_size,
                              hipStream_t stream) {
  const float* x      = (const float*)d_in[0];
  const float* W_in   = (const float*)d_in[1];
  const float* conv_w = (const float*)d_in[2];
  const float* conv_b = (const float*)d_in[3];
  const float* dt_b   = (const float*)d_in[4];
  const float* A_log  = (const float*)d_in[5];
  const float* Dvec   = (const float*)d_in[6];
  const float* norm_w = (const float*)d_in[7];
  const float* W_out  = (const float*)d_in[8];
  float* out = (float*)d_out;

  u16* zb       = (u16*)d_ws;                              // 33.55 MB
  u16* xbc      = zb + (size_t)B_ * L_ * DI;               // 37.75 MB
  float* dtp    = (float*)(xbc + (size_t)B_ * L_ * CONVD); // 1.05 MB
  float* Acs    = dtp + (size_t)B_ * L_ * NH;              // 1.05 MB
  u16* stregion = (u16*)(Acs + (size_t)B_ * NH * L_);      // 33.55 MB region
  u16* uni      = stregion + (size_t)B_ * NC * NH * HD * DS * 2;  // 37.75 MB
  u16* xraw = uni;
  u16* v    = uni;   // v = gated SSD output, aliases xraw

  // stregion: xb16@0 | wint@16.78M | woutt@25.69M | psum@29.88M ; states16@0
  u16* xb16     = stregion;
  u16* wint     = stregion + (size_t)B_ * L_ * DM;
  u16* woutt    = wint + (size_t)NGEMM * DM;
  float* psum   = (float*)(woutt + (size_t)DM * DI);
  u16* states16 = stregion;   // reuses xb16/wint space after gemm_in

  const int Mrows = B_ * L_;

  prep_k<<<1024 + (NGEMM / 64) * (DM / 64) + (DM / 64) * (DI / 64), 256, 0, stream>>>(
      x, W_in, W_out, norm_w, dt_b, dtp, xb16, wint, woutt);

  const int nwg_in = (Mrows / 256) * (NGEMM / 128);   // 1088
  gemm_in_k<<<nwg_in, 512, 0, stream>>>(xb16, wint, zb, xraw, nwg_in);

  conv_silu_k<<<(Mrows * (CONVD / 8)) / 256, 256, 0, stream>>>(xraw, conv_w, conv_b, xbc);
  states_k<<<B_ * NC * NH, 256, 0, stream>>>(xbc, dtp, A_log, Acs, states16);
  scan_k<<<B_ * NH * 16, 256, 0, stream>>>(states16, Acs);
  ssd_out_k<<<B_ * NC * NH, 512, 0, stream>>>(xbc, dtp, Acs, states16, Dvec,
                                              zb, v, psum);

  const int nwg_out = (Mrows / 128) * (DM / 128);     // 512
  gemm_out_k<DI, DM / 128><<<nwg_out, 256, 0, stream>>>(v, woutt, psum, out, nwg_out);
}